// Round 10
// baseline (249.549 us; speedup 1.0000x reference)
//
#include <hip/hip_runtime.h>
#include <hip/hip_bf16.h>
#include <hip/hip_cooperative_groups.h>

namespace cg = cooperative_groups;

// GAT layer, algebraically collapsed (validated math, absmax 0.0 in R2-R8):
//   u[b,n] = h . (W a1), v[b,n] = h . (W a2)
//   d_i = e^{u_i}*Sum_{v_j>-u_i} e^{v_j} + e^{.2u_i}*Sum_{<=} e^{.2v_j}
//   c_j = e^{v_j}*Sum_{u_i>-v_j} e^{u_i}/d_i + e^{.2v_j}*Sum_{<=} e^{.2u_i}/d_i
//   out[b,:] = (1/N) * (Sum_j c_j h[b,j,:]) @ W
// R8's four kernel bodies UNCHANGED, as one cooperative kernel with 3
// cg::grid.sync() instead of 3 extra dispatches. Tests whether the ~17us
// residual is dispatch-boundary cost. (R6's hand-rolled 95us barrier was a
// naive cross-XCD spin; hipLaunchCooperativeKernel is the supported path.)

#define B 8
#define N 2048
#define BN (B * N)
#define FIN 128
#define FOUT 64
#define ALPHA 0.2f
#define JS 64           // partial slices (32 elems each)
#define SJ (N / JS)     // 32 staged elements per pass phase

__device__ __forceinline__ float dot4(float4 x, float4 y) {
    return x.x * y.x + x.y * y.y + x.z * y.z + x.w * y.w;
}

__global__ __launch_bounds__(256, 2) void gat_coop(
        const float* __restrict__ h, const float* __restrict__ W,
        const float* __restrict__ a, float* __restrict__ u, float* __restrict__ v,
        float* __restrict__ Ap, float* __restrict__ Bp, float* __restrict__ cp,
        float* __restrict__ out) {
    cg::grid_group grid = cg::this_grid();
    const int t = threadIdx.x;
    const int bid = blockIdx.x;

    // ---- Phase A: u,v for 32 nodes/block; block 0 zeroes out[] ----
    {
        __shared__ float sa[2 * FOUT];
        __shared__ float sw[2 * FIN];
        if (bid == 0) {
            out[t] = 0.f;
            out[t + 256] = 0.f;
        }
        if (t < 2 * FOUT) sa[t] = a[t];
        __syncthreads();
        {   // w1[k] = W[k,:].a1, w2[k] = W[k,:].a2 ; k = t>>1, half covers 32 f's
            int k = t >> 1, half = t & 1;
            float p1 = 0.f, p2 = 0.f;
            #pragma unroll
            for (int i = 0; i < 8; ++i) {
                float4 w4 = *(const float4*)(W + k * FOUT + half * 32 + i * 4);
                float4 a1 = *(const float4*)(sa + half * 32 + i * 4);
                float4 a2 = *(const float4*)(sa + FOUT + half * 32 + i * 4);
                p1 += dot4(w4, a1);
                p2 += dot4(w4, a2);
            }
            p1 += __shfl_xor(p1, 1);
            p2 += __shfl_xor(p2, 1);
            if (half == 0) { sw[k] = p1; sw[FIN + k] = p2; }
        }
        __syncthreads();
        int wave = t >> 6, lane = t & 63;
        int hl = lane & 31;
        const float4 w1x = *(const float4*)(sw + hl * 4);
        const float4 w2x = *(const float4*)(sw + FIN + hl * 4);
        int node0 = bid * 32 + wave * 8;
        #pragma unroll
        for (int it = 0; it < 4; ++it) {
            int node = node0 + it * 2 + (lane >> 5);
            const float4 hx = *(const float4*)(h + (size_t)node * FIN + hl * 4);
            float p1 = dot4(hx, w1x);
            float p2 = dot4(hx, w2x);
            #pragma unroll
            for (int o = 1; o < 32; o <<= 1) {
                p1 += __shfl_xor(p1, o);
                p2 += __shfl_xor(p2, o);
            }
            if (hl == 0) { u[node] = p1; v[node] = p2; }
        }
    }
    grid.sync();

    // ---- Phase B: pass-1 partials. bid = b(8) x js(64); 8 rows/thread ----
    {
        __shared__ float sv[SJ], se[SJ], sf[SJ];
        int b = bid >> 6, js = bid & 63;
        if (t < SJ) {
            float vj = v[b * N + js * SJ + t];
            sv[t] = vj;
            se[t] = expf(vj);
            sf[t] = expf(ALPHA * vj);
        }
        __syncthreads();
        float th[8], A[8], Bm[8];
        #pragma unroll
        for (int r = 0; r < 8; ++r) {
            th[r] = -u[b * N + r * 256 + t];
            A[r] = 0.f; Bm[r] = 0.f;
        }
        #pragma unroll
        for (int j = 0; j < SJ; j += 4) {
            float4 vv = *(const float4*)&sv[j];
            float4 ee = *(const float4*)&se[j];
            float4 ff = *(const float4*)&sf[j];
            #pragma unroll
            for (int r = 0; r < 8; ++r) {
                A[r] += (vv.x > th[r]) ? ee.x : 0.f;  Bm[r] += (vv.x > th[r]) ? 0.f : ff.x;
                A[r] += (vv.y > th[r]) ? ee.y : 0.f;  Bm[r] += (vv.y > th[r]) ? 0.f : ff.y;
                A[r] += (vv.z > th[r]) ? ee.z : 0.f;  Bm[r] += (vv.z > th[r]) ? 0.f : ff.z;
                A[r] += (vv.w > th[r]) ? ee.w : 0.f;  Bm[r] += (vv.w > th[r]) ? 0.f : ff.w;
            }
        }
        #pragma unroll
        for (int r = 0; r < 8; ++r) {
            int i = r * 256 + t;
            Ap[js * BN + b * N + i] = A[r];
            Bp[js * BN + b * N + i] = Bm[r];
        }
    }
    grid.sync();

    // ---- Phase C: pass-2. bid = b(8) x is(64); 32-i slice, all 2048 j ----
    {
        __shared__ float spA[256], spB[256];
        __shared__ float su[SJ], sr1[SJ], sr2[SJ];
        int b = bid >> 6, is = bid & 63;
        {   // reduce 64 partials for 32 i's (8 chunks of 8)
            int n = t & 31, ch = t >> 5;
            int ii0 = b * N + is * 32 + n;
            float pA = 0.f, pB = 0.f;
            #pragma unroll
            for (int s2 = 0; s2 < 8; ++s2) {
                int s = ch * 8 + s2;
                pA += Ap[s * BN + ii0];
                pB += Bp[s * BN + ii0];
            }
            spA[ch * 32 + n] = pA;
            spB[ch * 32 + n] = pB;
        }
        __syncthreads();
        if (t < 32) {
            float As = 0.f, Bs = 0.f;
            #pragma unroll
            for (int ch = 0; ch < 8; ++ch) {
                As += spA[ch * 32 + t];
                Bs += spB[ch * 32 + t];
            }
            float ui = u[b * N + is * 32 + t];
            float eu = expf(ui);
            float fu = expf(ALPHA * ui);
            float inv = 1.0f / (eu * As + fu * Bs);
            su[t] = ui; sr1[t] = eu * inv; sr2[t] = fu * inv;
        }
        __syncthreads();
        float vj[8], th[8], Cn[8], Dn[8];
        #pragma unroll
        for (int r = 0; r < 8; ++r) {
            vj[r] = v[b * N + r * 256 + t];
            th[r] = -vj[r];
            Cn[r] = 0.f; Dn[r] = 0.f;
        }
        #pragma unroll
        for (int i = 0; i < SJ; i += 4) {
            float4 uu = *(const float4*)&su[i];
            float4 r1 = *(const float4*)&sr1[i];
            float4 r2 = *(const float4*)&sr2[i];
            #pragma unroll
            for (int r = 0; r < 8; ++r) {
                Cn[r] += (uu.x > th[r]) ? r1.x : 0.f;  Dn[r] += (uu.x > th[r]) ? 0.f : r2.x;
                Cn[r] += (uu.y > th[r]) ? r1.y : 0.f;  Dn[r] += (uu.y > th[r]) ? 0.f : r2.y;
                Cn[r] += (uu.z > th[r]) ? r1.z : 0.f;  Dn[r] += (uu.z > th[r]) ? 0.f : r2.z;
                Cn[r] += (uu.w > th[r]) ? r1.w : 0.f;  Dn[r] += (uu.w > th[r]) ? 0.f : r2.w;
            }
        }
        #pragma unroll
        for (int r = 0; r < 8; ++r) {
            int j = r * 256 + t;
            cp[is * BN + b * N + j] = expf(vj[r]) * Cn[r] + expf(ALPHA * vj[r]) * Dn[r];
        }
    }
    grid.sync();

    // ---- Phase D: epilogue. bid = b(8) x ns(64): c, g, out += g@W/N ----
    {
        __shared__ float scp[256];
        __shared__ float sc[32];
        __shared__ float sg2[256];
        __shared__ float sg[128];
        __shared__ float so[256];
        int b = bid >> 6, ns = bid & 63;
        {   // reduce 64 cp partials for 32 nodes (8 chunks of 8)
            int n = t & 31, ch = t >> 5;
            int nn = b * N + ns * 32 + n;
            float c = 0.f;
            #pragma unroll
            for (int s2 = 0; s2 < 8; ++s2) c += cp[(ch * 8 + s2) * BN + nn];
            scp[ch * 32 + n] = c;
        }
        __syncthreads();
        if (t < 32) {
            float c = 0.f;
            #pragma unroll
            for (int ch = 0; ch < 8; ++ch) c += scp[ch * 32 + t];
            sc[t] = c;
        }
        __syncthreads();
        {   // g[k] = sum over 32 nodes of c_n * h[n,k]
            int k = t & 127, half = t >> 7;
            float a0 = 0.f, a1 = 0.f;
            int base = b * N + ns * 32 + half * 16;
            #pragma unroll
            for (int n = 0; n < 16; n += 2) {
                a0 += sc[half * 16 + n]     * h[(size_t)(base + n)     * FIN + k];
                a1 += sc[half * 16 + n + 1] * h[(size_t)(base + n + 1) * FIN + k];
            }
            sg2[half * 128 + k] = a0 + a1;
        }
        __syncthreads();
        if (t < 128) sg[t] = sg2[t] + sg2[128 + t];
        __syncthreads();
        {   // out_part[f] = sum_k sg[k] * W[k,f]
            int f = t & 63, q = t >> 6;
            float acc = 0.f;
            #pragma unroll
            for (int kk2 = 0; kk2 < 32; ++kk2) {
                int kk = q * 32 + kk2;
                acc += sg[kk] * W[kk * FOUT + f];
            }
            so[q * 64 + f] = acc;
        }
        __syncthreads();
        if (t < 64) {
            float r = ((so[t] + so[64 + t]) + (so[128 + t] + so[192 + t])) * (1.0f / (float)N);
            atomicAdd(out + b * FOUT + t, r);
        }
    }
}

extern "C" void kernel_launch(void* const* d_in, const int* in_sizes, int n_in,
                              void* d_out, int out_size, void* d_ws, size_t ws_size,
                              hipStream_t stream) {
    const float* h = (const float*)d_in[0];  // [B,N,FIN]
    const float* W = (const float*)d_in[1];  // [FIN,FOUT]
    const float* a = (const float*)d_in[2];  // [2*FOUT]
    float* out = (float*)d_out;              // [B,FOUT]

    float* ws = (float*)d_ws;
    float* u  = ws;               // BN
    float* v  = u + BN;           // BN
    float* Ap = v + BN;           // JS*BN
    float* Bp = Ap + JS * BN;     // JS*BN
    float* cp = Bp + JS * BN;     // JS*BN

    void* args[] = {(void*)&h, (void*)&W, (void*)&a, (void*)&u, (void*)&v,
                    (void*)&Ap, (void*)&Bp, (void*)&cp, (void*)&out};
    hipLaunchCooperativeKernel((void*)gat_coop, dim3(512), dim3(256), args, 0, stream);
}

// Round 11
// 84.367 us; speedup vs baseline: 2.9579x; 2.9579x over previous
//
#include <hip/hip_runtime.h>
#include <hip/hip_bf16.h>

// GAT layer, algebraically collapsed (validated math, absmax 0.0 in R2-R8):
//   u[b,n] = h . (W a1), v[b,n] = h . (W a2)
//   d_i = e^{u_i}*Sum_{v_j>-u_i} e^{v_j} + e^{.2u_i}*Sum_{<=} e^{.2v_j}
//   c_j = e^{v_j}*Sum_{u_i>-v_j} e^{u_i}/d_i + e^{.2v_j}*Sum_{<=} e^{.2u_i}/d_i
//   out[b,:] = (1/N) * (Sum_j c_j h[b,j,:]) @ W
// FINAL FORM (= R8, best measured: 84.9us). Sync-mechanism ledger:
//   dispatch boundary ~0-4us  <  grid.sync ~55us  <  hand barrier ~95us
// so 4 discrete dispatches is optimal for the 3 global syncs this DAG needs.
// Bodies sit at their VALU/LDS-issue floors (~2.1us per O(N^2) pass).

#define B 8
#define N 2048
#define BN (B * N)
#define FIN 128
#define FOUT 64
#define ALPHA 0.2f
#define JS 64           // partial slices (32 elems each)
#define SJ (N / JS)     // 32 staged elements per pass block

__device__ __forceinline__ float dot4(float4 x, float4 y) {
    return x.x * y.x + x.y * y.y + x.z * y.z + x.w * y.w;
}

// ---------------- K2: u,v per node. 512 blocks x 256 thr, 32 nodes/block.
// Projection: thread (k=t>>1, half=t&1) covers 32 f's -> 2 shfl to combine.
// Main loop: one float4 load covers 2 nodes per wave; 5-level half-wave reduce.
// Block 0 zero-inits out[] for K5's atomics.
__global__ __launch_bounds__(256) void k2_uv(const float* __restrict__ h,
                                             const float* __restrict__ W,
                                             const float* __restrict__ a,
                                             float* __restrict__ u, float* __restrict__ v,
                                             float* __restrict__ out) {
    __shared__ float sa[2 * FOUT];
    __shared__ float sw[2 * FIN];
    int t = threadIdx.x, bid = blockIdx.x;
    if (bid == 0) {   // zero the 512-float output for K5's atomicAdds
        out[t] = 0.f;
        out[t + 256] = 0.f;
    }
    if (t < 2 * FOUT) sa[t] = a[t];
    __syncthreads();
    {   // w1[k] = W[k,:].a1, w2[k] = W[k,:].a2 ; k = t>>1, half covers 32 f's
        int k = t >> 1, half = t & 1;
        float p1 = 0.f, p2 = 0.f;
        #pragma unroll
        for (int i = 0; i < 8; ++i) {
            float4 w4 = *(const float4*)(W + k * FOUT + half * 32 + i * 4);
            float4 a1 = *(const float4*)(sa + half * 32 + i * 4);
            float4 a2 = *(const float4*)(sa + FOUT + half * 32 + i * 4);
            p1 += dot4(w4, a1);
            p2 += dot4(w4, a2);
        }
        p1 += __shfl_xor(p1, 1);
        p2 += __shfl_xor(p2, 1);
        if (half == 0) { sw[k] = p1; sw[FIN + k] = p2; }
    }
    __syncthreads();
    int wave = t >> 6, lane = t & 63;
    int hl = lane & 31;              // lane within half-wave
    const float4 w1x = *(const float4*)(sw + hl * 4);
    const float4 w2x = *(const float4*)(sw + FIN + hl * 4);
    int node0 = bid * 32 + wave * 8;
    #pragma unroll
    for (int it = 0; it < 4; ++it) {
        int node = node0 + it * 2 + (lane >> 5);   // 2 nodes per wave-iter
        const float4 hx = *(const float4*)(h + (size_t)node * FIN + hl * 4);
        float p1 = dot4(hx, w1x);
        float p2 = dot4(hx, w2x);
        #pragma unroll
        for (int o = 1; o < 32; o <<= 1) {
            p1 += __shfl_xor(p1, o);
            p2 += __shfl_xor(p2, o);
        }
        if (hl == 0) { u[node] = p1; v[node] = p2; }
    }
}

// ---------------- K3: pass-1 partials. 512 blocks = b(8) x js(64).
// IR=8 rows/thread (covers all 2048 i); SJ=32 j's staged in LDS.
__global__ __launch_bounds__(256) void k3_pass1(const float* __restrict__ u,
                                                const float* __restrict__ v,
                                                float* __restrict__ Ap, float* __restrict__ Bp) {
    __shared__ float sv[SJ], se[SJ], sf[SJ];
    int bid = blockIdx.x;
    int b = bid >> 6, js = bid & 63;
    int t = threadIdx.x;
    if (t < SJ) {
        float vj = v[b * N + js * SJ + t];
        sv[t] = vj;
        se[t] = expf(vj);
        sf[t] = expf(ALPHA * vj);
    }
    __syncthreads();
    float th[8], A[8], Bm[8];
    #pragma unroll
    for (int r = 0; r < 8; ++r) {
        th[r] = -u[b * N + r * 256 + t];
        A[r] = 0.f; Bm[r] = 0.f;
    }
    #pragma unroll
    for (int j = 0; j < SJ; j += 4) {
        float4 vv = *(const float4*)&sv[j];
        float4 ee = *(const float4*)&se[j];
        float4 ff = *(const float4*)&sf[j];
        #pragma unroll
        for (int r = 0; r < 8; ++r) {
            A[r] += (vv.x > th[r]) ? ee.x : 0.f;  Bm[r] += (vv.x > th[r]) ? 0.f : ff.x;
            A[r] += (vv.y > th[r]) ? ee.y : 0.f;  Bm[r] += (vv.y > th[r]) ? 0.f : ff.y;
            A[r] += (vv.z > th[r]) ? ee.z : 0.f;  Bm[r] += (vv.z > th[r]) ? 0.f : ff.z;
            A[r] += (vv.w > th[r]) ? ee.w : 0.f;  Bm[r] += (vv.w > th[r]) ? 0.f : ff.w;
        }
    }
    #pragma unroll
    for (int r = 0; r < 8; ++r) {
        int i = r * 256 + t;
        Ap[js * BN + b * N + i] = A[r];
        Bp[js * BN + b * N + i] = Bm[r];
    }
}

// ---------------- K4: pass-2. 512 blocks = b(8) x is(64).
// Reduces 64 pass-1 partials for its 32-i slice, forms d_i, r1, r2 in LDS,
// then accumulates c_j partials for all 2048 j's (8 rows/thread).
__global__ __launch_bounds__(256) void k4_pass2(const float* __restrict__ u,
                                                const float* __restrict__ v,
                                                const float* __restrict__ Ap,
                                                const float* __restrict__ Bp,
                                                float* __restrict__ cp) {
    __shared__ float spA[256], spB[256];
    __shared__ float su[SJ], sr1[SJ], sr2[SJ];
    int bid = blockIdx.x;
    int b = bid >> 6, is = bid & 63;
    int t = threadIdx.x;
    {   // reduce 64 partials for 32 i's (8 chunks of 8 across threads)
        int n = t & 31, ch = t >> 5;
        int ii0 = b * N + is * 32 + n;
        float pA = 0.f, pB = 0.f;
        #pragma unroll
        for (int s2 = 0; s2 < 8; ++s2) {
            int s = ch * 8 + s2;
            pA += Ap[s * BN + ii0];
            pB += Bp[s * BN + ii0];
        }
        spA[ch * 32 + n] = pA;
        spB[ch * 32 + n] = pB;
    }
    __syncthreads();
    if (t < 32) {
        float As = 0.f, Bs = 0.f;
        #pragma unroll
        for (int ch = 0; ch < 8; ++ch) {
            As += spA[ch * 32 + t];
            Bs += spB[ch * 32 + t];
        }
        float ui = u[b * N + is * 32 + t];
        float eu = expf(ui);
        float fu = expf(ALPHA * ui);
        float inv = 1.0f / (eu * As + fu * Bs);
        su[t] = ui; sr1[t] = eu * inv; sr2[t] = fu * inv;
    }
    __syncthreads();
    float vj[8], th[8], Cn[8], Dn[8];
    #pragma unroll
    for (int r = 0; r < 8; ++r) {
        vj[r] = v[b * N + r * 256 + t];
        th[r] = -vj[r];
        Cn[r] = 0.f; Dn[r] = 0.f;
    }
    #pragma unroll
    for (int i = 0; i < SJ; i += 4) {
        float4 uu = *(const float4*)&su[i];
        float4 r1 = *(const float4*)&sr1[i];
        float4 r2 = *(const float4*)&sr2[i];
        #pragma unroll
        for (int r = 0; r < 8; ++r) {
            Cn[r] += (uu.x > th[r]) ? r1.x : 0.f;  Dn[r] += (uu.x > th[r]) ? 0.f : r2.x;
            Cn[r] += (uu.y > th[r]) ? r1.y : 0.f;  Dn[r] += (uu.y > th[r]) ? 0.f : r2.y;
            Cn[r] += (uu.z > th[r]) ? r1.z : 0.f;  Dn[r] += (uu.z > th[r]) ? 0.f : r2.z;
            Cn[r] += (uu.w > th[r]) ? r1.w : 0.f;  Dn[r] += (uu.w > th[r]) ? 0.f : r2.w;
        }
    }
    #pragma unroll
    for (int r = 0; r < 8; ++r) {
        int j = r * 256 + t;
        cp[is * BN + b * N + j] = expf(vj[r]) * Cn[r] + expf(ALPHA * vj[r]) * Dn[r];
    }
}

// ---------------- K5: fused epilogue. 512 blocks = b(8) x ns(64), 256 thr.
// c_n = Sum_s cp[s][n] (64 partials) for 32 nodes; g[128] = Sum_n c_n h[n,:];
// out[b,f] += (1/N) * Sum_k g[k] W[k,f]  (atomicAdd, out zeroed by K2).
__global__ __launch_bounds__(256) void k5_out(const float* __restrict__ h,
                                              const float* __restrict__ W,
                                              const float* __restrict__ cp,
                                              float* __restrict__ out) {
    __shared__ float scp[256];   // 8 chunks x 32 nodes
    __shared__ float sc[32];
    __shared__ float sg2[256];   // 2 x 128
    __shared__ float sg[128];
    __shared__ float so[256];    // 4 x 64
    int b = blockIdx.x >> 6, ns = blockIdx.x & 63;
    int t = threadIdx.x;
    {   // reduce 64 cp partials for 32 nodes (8 chunks of 8)
        int n = t & 31, ch = t >> 5;
        int nn = b * N + ns * 32 + n;
        float c = 0.f;
        #pragma unroll
        for (int s2 = 0; s2 < 8; ++s2) c += cp[(ch * 8 + s2) * BN + nn];
        scp[ch * 32 + n] = c;
    }
    __syncthreads();
    if (t < 32) {
        float c = 0.f;
        #pragma unroll
        for (int ch = 0; ch < 8; ++ch) c += scp[ch * 32 + t];
        sc[t] = c;
    }
    __syncthreads();
    {   // g[k] = sum over 32 nodes of c_n * h[n,k], split across two halves
        int k = t & 127, half = t >> 7;
        float a0 = 0.f, a1 = 0.f;
        int base = b * N + ns * 32 + half * 16;
        #pragma unroll
        for (int n = 0; n < 16; n += 2) {
            a0 += sc[half * 16 + n]     * h[(size_t)(base + n)     * FIN + k];
            a1 += sc[half * 16 + n + 1] * h[(size_t)(base + n + 1) * FIN + k];
        }
        sg2[half * 128 + k] = a0 + a1;
    }
    __syncthreads();
    if (t < 128) sg[t] = sg2[t] + sg2[128 + t];
    __syncthreads();
    {   // out_part[f] = sum_k sg[k] * W[k,f], k split in 4 quarters
        int f = t & 63, q = t >> 6;
        float acc = 0.f;
        #pragma unroll
        for (int kk2 = 0; kk2 < 32; ++kk2) {
            int kk = q * 32 + kk2;
            acc += sg[kk] * W[kk * FOUT + f];
        }
        so[q * 64 + f] = acc;
    }
    __syncthreads();
    if (t < 64) {
        float r = ((so[t] + so[64 + t]) + (so[128 + t] + so[192 + t])) * (1.0f / (float)N);
        atomicAdd(out + b * FOUT + t, r);
    }
}

extern "C" void kernel_launch(void* const* d_in, const int* in_sizes, int n_in,
                              void* d_out, int out_size, void* d_ws, size_t ws_size,
                              hipStream_t stream) {
    const float* h = (const float*)d_in[0];  // [B,N,FIN]
    const float* W = (const float*)d_in[1];  // [FIN,FOUT]
    const float* a = (const float*)d_in[2];  // [2*FOUT]
    float* out = (float*)d_out;              // [B,FOUT]

    float* ws = (float*)d_ws;
    float* u  = ws;               // BN
    float* v  = u + BN;           // BN
    float* Ap = v + BN;           // JS*BN
    float* Bp = Ap + JS * BN;     // JS*BN
    float* cp = Bp + JS * BN;     // JS*BN

    k2_uv<<<512, 256, 0, stream>>>(h, W, a, u, v, out);
    k3_pass1<<<512, 256, 0, stream>>>(u, v, Ap, Bp);
    k4_pass2<<<512, 256, 0, stream>>>(u, v, Ap, Bp, cp);
    k5_out<<<512, 256, 0, stream>>>(h, W, cp, out);
}